// Round 1
// baseline (1367.116 us; speedup 1.0000x reference)
//
#include <hip/hip_runtime.h>
#include <math.h>

#define B_ 8
#define C_ 3
#define HW_ 512
#define P_ 128
#define S_ 64
#define K_ 31
#define NZ_ 15
#define HID_ 64
#define NPOS_ 49   // 7x7 patch positions
#define BN_ (B_*NPOS_)

__device__ __forceinline__ float hann128(int p) {
    return 0.5f - 0.5f * cosf(6.283185307179586f * (float)p / 128.0f);
}

// ---------------------------------------------------------------------------
// Kernel 1: MLP + pupil + 31x31 DFT -> flipped, normalized conv kernel kf
// one block per patch position (49 blocks)
// ---------------------------------------------------------------------------
__global__ __launch_bounds__(256) void psf_kernel(
    const float* __restrict__ w1, const float* __restrict__ b1,
    const float* __restrict__ w2, const float* __restrict__ b2,
    const float* __restrict__ w3, const float* __restrict__ b3,
    const float* __restrict__ basis, float* __restrict__ kf_out)
{
    __shared__ float h1[HID_], h2[HID_], coef[NZ_];
    __shared__ float pupR[961], pupI[961], tR[961], tI[961];
    __shared__ float rootR[31], rootI[31];
    __shared__ float red[256];
    int n = blockIdx.x;
    int nh = n / 7, nw = n % 7;
    int tid = threadIdx.x;
    float cy = (float)(nh * S_ + P_ / 2) * (2.0f / (float)HW_) - 1.0f;
    float cx = (float)(nw * S_ + P_ / 2) * (2.0f / (float)HW_) - 1.0f;

    if (tid < HID_) h1[tid] = fmaxf(0.0f, cy * w1[tid] + cx * w1[HID_ + tid] + b1[tid]);
    if (tid < 31) {
        float ang = -6.283185307179586f * (float)tid / 31.0f;
        rootR[tid] = cosf(ang);
        rootI[tid] = sinf(ang);
    }
    __syncthreads();
    if (tid < HID_) {
        float s = b2[tid];
        for (int k = 0; k < HID_; ++k) s = fmaf(h1[k], w2[k * HID_ + tid], s);
        h2[tid] = fmaxf(0.0f, s);
    }
    __syncthreads();
    if (tid < NZ_) {
        float s = b3[tid];
        for (int k = 0; k < HID_; ++k) s = fmaf(h2[k], w3[k * NZ_ + tid], s);
        coef[tid] = s;
    }
    __syncthreads();

    // pupil = mask * exp(i*phase)
    for (int idx = tid; idx < 961; idx += 256) {
        int h = idx / 31, w = idx % 31;
        float ph = 0.0f;
        for (int z = 0; z < NZ_; ++z) ph = fmaf(coef[z], basis[z * 961 + idx], ph);
        int dh = h - 15, dw = w - 15;
        bool m = (dh * dh + dw * dw) <= 225;
        float sv, cv;
        sincosf(ph, &sv, &cv);
        pupR[idx] = m ? cv : 0.0f;
        pupI[idx] = m ? sv : 0.0f;
    }
    __syncthreads();

    // row DFT over w: t[h,k] = sum_w pup[h,w] * e^{-2pi i k w/31}
    for (int idx = tid; idx < 961; idx += 256) {
        int h = idx / 31, k = idx % 31;
        float ar = 0.0f, ai = 0.0f;
        for (int w = 0; w < 31; ++w) {
            int tt = (k * w) % 31;
            float cr = rootR[tt], ci = rootI[tt];
            float pr = pupR[h * 31 + w], pi = pupI[h * 31 + w];
            ar += pr * cr - pi * ci;
            ai += pr * ci + pi * cr;
        }
        tR[idx] = ar; tI[idx] = ai;
    }
    __syncthreads();

    // col DFT over h + |.|^2 -> psf_un[u,k] (reuse pupR), plus sum
    float lsum = 0.0f;
    for (int idx = tid; idx < 961; idx += 256) {
        int u = idx / 31, k = idx % 31;
        float gr = 0.0f, gi = 0.0f;
        for (int h = 0; h < 31; ++h) {
            int tt = (u * h) % 31;
            float cr = rootR[tt], ci = rootI[tt];
            float ar = tR[h * 31 + k], ai = tI[h * 31 + k];
            gr += ar * cr - ai * ci;
            gi += ar * ci + ai * cr;
        }
        float p = gr * gr + gi * gi;
        pupR[idx] = p;
        lsum += p;
    }
    red[tid] = lsum;
    __syncthreads();
    for (int off = 128; off > 0; off >>= 1) {
        if (tid < off) red[tid] += red[tid + off];
        __syncthreads();
    }
    float inv = 1.0f / (red[0] + 1e-12f);
    // psf[u,v] = psf_un[(u-15)%31, (v-15)%31];  kf[j,i] = psf[30-j,30-i]
    // => kf[j,i] = psf_un[(15-j)%31, (15-i)%31] * inv
    for (int idx = tid; idx < 961; idx += 256) {
        int j = idx / 31, i = idx % 31;
        int u = (15 - j + 31) % 31, v = (15 - i + 31) % 31;
        kf_out[n * 961 + idx] = pupR[u * 31 + v] * inv;
    }
}

// ---------------------------------------------------------------------------
// Kernel 2: per-patch depthwise 31x31 conv (zero-padded), windowed.
// MODE 0: write per-patch result to ws buffer. MODE 1: atomicAdd into d_out.
// grid: BN*C*4 blocks (2x2 tiles of 64x64), 256 threads, 4x4 regs/thread
// ---------------------------------------------------------------------------
template<int MODE>
__global__ __launch_bounds__(256) void conv_kernel(
    const float* __restrict__ x, const float* __restrict__ kf_all,
    float* __restrict__ dst)
{
    __shared__ float sIn[94][96];
    __shared__ float sK[961];
    int t = blockIdx.x;
    int tile = t & 3;
    int cc = (t >> 2) % 3;
    int bn = t / 12;
    int b = bn / NPOS_, n = bn % NPOS_;
    int nh = n / 7, nw = n % 7;
    int ty0 = (tile >> 1) * 64, tx0 = (tile & 1) * 64;
    int r0 = nh * S_, c0 = nw * S_;
    int tid = threadIdx.x;

    for (int i = tid; i < 961; i += 256) sK[i] = kf_all[n * 961 + i];
    const float* xb = x + ((size_t)(b * C_ + cc) * HW_ + r0) * HW_ + c0;
    for (int i = tid; i < 94 * 96; i += 256) {
        int r = i / 96, col = i % 96;
        if (col < 94) {
            int pr = ty0 - 15 + r, pc = tx0 - 15 + col;
            float v = 0.0f;
            if (pr >= 0 && pr < P_ && pc >= 0 && pc < P_) v = xb[pr * HW_ + pc];
            sIn[r][col] = v;
        }
    }
    __syncthreads();

    int tyT = tid >> 4, txT = tid & 15;
    int oy = tyT * 4, ox = txT * 4;
    float acc[4][4] = {};
    for (int j = 0; j < 31; ++j) {
        float kr[31];
        #pragma unroll
        for (int i = 0; i < 31; ++i) kr[i] = sK[j * 31 + i];
        for (int a = 0; a < 4; ++a) {
            const float* rowp = &sIn[oy + a + j][ox];
            float xv[34];
            #pragma unroll
            for (int i = 0; i < 34; ++i) xv[i] = rowp[i];
            #pragma unroll
            for (int i = 0; i < 31; ++i) {
                float kv = kr[i];
                acc[a][0] = fmaf(kv, xv[i + 0], acc[a][0]);
                acc[a][1] = fmaf(kv, xv[i + 1], acc[a][1]);
                acc[a][2] = fmaf(kv, xv[i + 2], acc[a][2]);
                acc[a][3] = fmaf(kv, xv[i + 3], acc[a][3]);
            }
        }
    }

    float hy[4], hx[4];
    #pragma unroll
    for (int q = 0; q < 4; ++q) {
        hy[q] = hann128(ty0 + oy + q);
        hx[q] = hann128(tx0 + ox + q);
    }
    if (MODE == 0) {
        float* yp = dst + (((size_t)bn * C_ + cc) << 14);
        #pragma unroll
        for (int a = 0; a < 4; ++a) {
            int py = ty0 + oy + a;
            float4 v;
            v.x = acc[a][0] * hy[a] * hx[0];
            v.y = acc[a][1] * hy[a] * hx[1];
            v.z = acc[a][2] * hy[a] * hx[2];
            v.w = acc[a][3] * hy[a] * hx[3];
            *(float4*)(yp + py * P_ + tx0 + ox) = v;
        }
    } else {
        float* ob = dst + ((size_t)(b * C_ + cc) * HW_ + r0) * HW_ + c0;
        for (int a = 0; a < 4; ++a)
            for (int q = 0; q < 4; ++q)
                atomicAdd(ob + (ty0 + oy + a) * HW_ + tx0 + ox + q,
                          acc[a][q] * hy[a] * hx[q]);
    }
}

// ---------------------------------------------------------------------------
// Kernel 3a: gather overlap-add from ws patch buffer, divide by analytic w
// ---------------------------------------------------------------------------
__global__ __launch_bounds__(256) void gather_kernel(
    const float* __restrict__ ypatch, float* __restrict__ out)
{
    int idx = blockIdx.x * 256 + threadIdx.x;
    if (idx >= B_ * C_ * HW_ * HW_) return;
    int X = idx & 511;
    int Y = (idx >> 9) & 511;
    int bc = idx >> 18;
    int c = bc % 3, b = bc / 3;
    int nhA = Y >> 6, pyA = Y & 63;
    int nwA = X >> 6, pxA = X & 63;
    bool vA = nhA <= 6, vB = nhA >= 1;
    bool uA = nwA <= 6, uB = nwA >= 1;
    float hyA = hann128(pyA), hyB = hann128(pyA + 64);
    float hxA = hann128(pxA), hxB = hann128(pxA + 64);
    float wy = (vA ? hyA : 0.0f) + (vB ? hyB : 0.0f);
    float wx = (uA ? hxA : 0.0f) + (uB ? hxB : 0.0f);

    float acc = 0.0f;
    #pragma unroll
    for (int sy = 0; sy < 2; ++sy) {
        bool okY = sy == 0 ? vA : vB;
        int nh = sy == 0 ? nhA : nhA - 1;
        int py = sy == 0 ? pyA : pyA + 64;
        #pragma unroll
        for (int sx = 0; sx < 2; ++sx) {
            bool okX = sx == 0 ? uA : uB;
            int nw = sx == 0 ? nwA : nwA - 1;
            int px = sx == 0 ? pxA : pxA + 64;
            if (okY && okX) {
                size_t off = ((((size_t)b * NPOS_ + nh * 7 + nw) * C_ + c) << 14) + (py << 7) + px;
                acc += ypatch[off];
            }
        }
    }
    out[idx] = acc / (wy * wx + 1e-8f);
}

// ---------------------------------------------------------------------------
// Kernel 3b: in-place divide (atomic fallback path)
// ---------------------------------------------------------------------------
__global__ __launch_bounds__(256) void divide_kernel(float* __restrict__ out)
{
    int idx = blockIdx.x * 256 + threadIdx.x;
    if (idx >= B_ * C_ * HW_ * HW_) return;
    int X = idx & 511;
    int Y = (idx >> 9) & 511;
    int nhA = Y >> 6, pyA = Y & 63;
    int nwA = X >> 6, pxA = X & 63;
    float wy = (nhA <= 6 ? hann128(pyA) : 0.0f) + (nhA >= 1 ? hann128(pyA + 64) : 0.0f);
    float wx = (nwA <= 6 ? hann128(pxA) : 0.0f) + (nwA >= 1 ? hann128(pxA + 64) : 0.0f);
    out[idx] = out[idx] / (wy * wx + 1e-8f);
}

extern "C" void kernel_launch(void* const* d_in, const int* in_sizes, int n_in,
                              void* d_out, int out_size, void* d_ws, size_t ws_size,
                              hipStream_t stream)
{
    const float* x    = (const float*)d_in[0];
    const float* w1   = (const float*)d_in[1];
    const float* b1   = (const float*)d_in[2];
    const float* w2   = (const float*)d_in[3];
    const float* b2   = (const float*)d_in[4];
    const float* w3   = (const float*)d_in[5];
    const float* b3   = (const float*)d_in[6];
    const float* basis = (const float*)d_in[7];
    float* out = (float*)d_out;

    float* kf = (float*)d_ws;
    size_t kfBytes = ((size_t)NPOS_ * 961 * sizeof(float) + 255) & ~(size_t)255;
    size_t need = kfBytes + (size_t)BN_ * C_ * P_ * P_ * sizeof(float);

    psf_kernel<<<NPOS_, 256, 0, stream>>>(w1, b1, w2, b2, w3, b3, basis, kf);

    int nPix = B_ * C_ * HW_ * HW_;
    if (ws_size >= need) {
        float* ypatch = (float*)((char*)d_ws + kfBytes);
        conv_kernel<0><<<BN_ * C_ * 4, 256, 0, stream>>>(x, kf, ypatch);
        gather_kernel<<<(nPix + 255) / 256, 256, 0, stream>>>(ypatch, out);
    } else {
        hipMemsetAsync(d_out, 0, (size_t)out_size * sizeof(float), stream);
        conv_kernel<1><<<BN_ * C_ * 4, 256, 0, stream>>>(x, kf, out);
        divide_kernel<<<(nPix + 255) / 256, 256, 0, stream>>>(out);
    }
}

// Round 2
// 1215.389 us; speedup vs baseline: 1.1248x; 1.1248x over previous
//
#include <hip/hip_runtime.h>
#include <math.h>

#define B_ 8
#define C_ 3
#define HW_ 512
#define P_ 128
#define S_ 64
#define K_ 31
#define NZ_ 15
#define HID_ 64
#define NPOS_ 49   // 7x7 patch positions
#define BN_ (B_*NPOS_)

#define INROWS_ 94          // 64 + 30 halo
#define INSTRIDE_ 104       // floats; 104 mod 32 = 8 -> conflict-free row spread; 416B row, 16B aligned

__device__ __forceinline__ float hann128(int p) {
    return 0.5f - 0.5f * cosf(6.283185307179586f * (float)p / 128.0f);
}

// ---------------------------------------------------------------------------
// Kernel 1: MLP + pupil + 31x31 DFT -> flipped, normalized conv kernel kf
// one block per patch position (49 blocks)
// ---------------------------------------------------------------------------
__global__ __launch_bounds__(256) void psf_kernel(
    const float* __restrict__ w1, const float* __restrict__ b1,
    const float* __restrict__ w2, const float* __restrict__ b2,
    const float* __restrict__ w3, const float* __restrict__ b3,
    const float* __restrict__ basis, float* __restrict__ kf_out)
{
    __shared__ float h1[HID_], h2[HID_], coef[NZ_];
    __shared__ float pupR[961], pupI[961], tR[961], tI[961];
    __shared__ float rootR[31], rootI[31];
    __shared__ float red[256];
    int n = blockIdx.x;
    int nh = n / 7, nw = n % 7;
    int tid = threadIdx.x;
    float cy = (float)(nh * S_ + P_ / 2) * (2.0f / (float)HW_) - 1.0f;
    float cx = (float)(nw * S_ + P_ / 2) * (2.0f / (float)HW_) - 1.0f;

    if (tid < HID_) h1[tid] = fmaxf(0.0f, cy * w1[tid] + cx * w1[HID_ + tid] + b1[tid]);
    if (tid < 31) {
        float ang = -6.283185307179586f * (float)tid / 31.0f;
        rootR[tid] = cosf(ang);
        rootI[tid] = sinf(ang);
    }
    __syncthreads();
    if (tid < HID_) {
        float s = b2[tid];
        for (int k = 0; k < HID_; ++k) s = fmaf(h1[k], w2[k * HID_ + tid], s);
        h2[tid] = fmaxf(0.0f, s);
    }
    __syncthreads();
    if (tid < NZ_) {
        float s = b3[tid];
        for (int k = 0; k < HID_; ++k) s = fmaf(h2[k], w3[k * NZ_ + tid], s);
        coef[tid] = s;
    }
    __syncthreads();

    // pupil = mask * exp(i*phase)
    for (int idx = tid; idx < 961; idx += 256) {
        int h = idx / 31, w = idx % 31;
        float ph = 0.0f;
        for (int z = 0; z < NZ_; ++z) ph = fmaf(coef[z], basis[z * 961 + idx], ph);
        int dh = h - 15, dw = w - 15;
        bool m = (dh * dh + dw * dw) <= 225;
        float sv, cv;
        sincosf(ph, &sv, &cv);
        pupR[idx] = m ? cv : 0.0f;
        pupI[idx] = m ? sv : 0.0f;
    }
    __syncthreads();

    // row DFT over w: t[h,k] = sum_w pup[h,w] * e^{-2pi i k w/31}
    for (int idx = tid; idx < 961; idx += 256) {
        int h = idx / 31, k = idx % 31;
        float ar = 0.0f, ai = 0.0f;
        for (int w = 0; w < 31; ++w) {
            int tt = (k * w) % 31;
            float cr = rootR[tt], ci = rootI[tt];
            float pr = pupR[h * 31 + w], pi = pupI[h * 31 + w];
            ar += pr * cr - pi * ci;
            ai += pr * ci + pi * cr;
        }
        tR[idx] = ar; tI[idx] = ai;
    }
    __syncthreads();

    // col DFT over h + |.|^2 -> psf_un[u,k] (reuse pupR), plus sum
    float lsum = 0.0f;
    for (int idx = tid; idx < 961; idx += 256) {
        int u = idx / 31, k = idx % 31;
        float gr = 0.0f, gi = 0.0f;
        for (int h = 0; h < 31; ++h) {
            int tt = (u * h) % 31;
            float cr = rootR[tt], ci = rootI[tt];
            float ar = tR[h * 31 + k], ai = tI[h * 31 + k];
            gr += ar * cr - ai * ci;
            gi += ar * ci + ai * cr;
        }
        float p = gr * gr + gi * gi;
        pupR[idx] = p;
        lsum += p;
    }
    red[tid] = lsum;
    __syncthreads();
    for (int off = 128; off > 0; off >>= 1) {
        if (tid < off) red[tid] += red[tid + off];
        __syncthreads();
    }
    float inv = 1.0f / (red[0] + 1e-12f);
    // kf[j,i] = psf_un[(15-j)%31, (15-i)%31] * inv
    for (int idx = tid; idx < 961; idx += 256) {
        int j = idx / 31, i = idx % 31;
        int u = (15 - j + 31) % 31, v = (15 - i + 31) % 31;
        kf_out[n * 961 + idx] = pupR[u * 31 + v] * inv;
    }
}

// ---------------------------------------------------------------------------
// Kernel 2 (v2): per-patch depthwise 31x31 conv, windowed.
// grid: BN*C*4 blocks (2x2 tiles of 64x64), 256 threads.
// Thread strip = 2 rows x 8 cols. Wave layout: ty=lane>>3 (8 ADJACENT rows),
// tx=lane&7 (8-col strips). Row stride 104 floats => 2-way max bank aliasing
// (free). 10 ds_read_b128 per 248 FMAs.
// ---------------------------------------------------------------------------
template<int MODE>
__global__ __launch_bounds__(256, 3) void conv_kernel(
    const float* __restrict__ x, const float* __restrict__ kf_all,
    float* __restrict__ dst)
{
    __shared__ float sIn[INROWS_ * INSTRIDE_];  // 94*104*4 = 39104 B
    __shared__ float sK[31 * 32];               // 3968 B

    int t = blockIdx.x;
    int tile = t & 3;
    int cc = (t >> 2) % 3;
    int bn = t / 12;
    int b = bn / NPOS_, n = bn % NPOS_;
    int nh = n / 7, nw = n % 7;
    int ty0 = (tile >> 1) * 64, tx0 = (tile & 1) * 64;
    int r0 = nh * S_, c0 = nw * S_;
    int tid = threadIdx.x;

    // kernel -> LDS, rows padded to 32
    for (int i = tid; i < 31 * 32; i += 256) {
        int j = i >> 5, q = i & 31;
        sK[i] = (q < 31) ? kf_all[n * 961 + j * 31 + q] : 0.0f;
    }
    // input tile (zero-padded patch semantics) -> LDS, 94 rows x 96 cols used
    const float* xb = x + ((size_t)(b * C_ + cc) * HW_ + r0) * HW_ + c0;
    for (int i = tid; i < INROWS_ * 96; i += 256) {
        int r = i / 96, c = i % 96;
        int pr = ty0 - 15 + r, pc = tx0 - 15 + c;
        float v = 0.0f;
        if (pr >= 0 && pr < P_ && pc >= 0 && pc < P_) v = xb[pr * HW_ + pc];
        sIn[r * INSTRIDE_ + c] = v;
    }
    __syncthreads();

    int lane = tid & 63, w = tid >> 6;
    int ty = lane >> 3, tx = lane & 7;
    int ox = tx * 8;
    // output rows: y(k) = w*16 + ty + 8*k, k = 0,1
    float acc[2][8] = {};

    #pragma unroll 1
    for (int j = 0; j < 31; ++j) {
        float kr[32];
        float4* krv = (float4*)kr;
        #pragma unroll
        for (int q = 0; q < 8; ++q) krv[q] = *(const float4*)&sK[j * 32 + q * 4];
        #pragma unroll
        for (int k = 0; k < 2; ++k) {
            int r = w * 16 + ty + 8 * k + j;        // sIn row = y + j
            const float* rp = &sIn[r * INSTRIDE_ + ox];
            float xv[40];
            float4* xvv = (float4*)xv;
            #pragma unroll
            for (int q = 0; q < 10; ++q) xvv[q] = *(const float4*)&rp[q * 4];
            #pragma unroll
            for (int i = 0; i < 31; ++i) {
                float kv = kr[i];
                #pragma unroll
                for (int q = 0; q < 8; ++q)
                    acc[k][q] = fmaf(kv, xv[i + q], acc[k][q]);
            }
        }
    }

    float hx[8];
    #pragma unroll
    for (int q = 0; q < 8; ++q) hx[q] = hann128(tx0 + ox + q);

    #pragma unroll
    for (int k = 0; k < 2; ++k) {
        int y = w * 16 + ty + 8 * k;
        float hy = hann128(ty0 + y);
        if (MODE == 0) {
            float* yp = dst + (((size_t)bn * C_ + cc) << 14) + (ty0 + y) * P_ + tx0 + ox;
            float4 v0, v1;
            v0.x = acc[k][0] * hy * hx[0]; v0.y = acc[k][1] * hy * hx[1];
            v0.z = acc[k][2] * hy * hx[2]; v0.w = acc[k][3] * hy * hx[3];
            v1.x = acc[k][4] * hy * hx[4]; v1.y = acc[k][5] * hy * hx[5];
            v1.z = acc[k][6] * hy * hx[6]; v1.w = acc[k][7] * hy * hx[7];
            *(float4*)yp = v0;
            *(float4*)(yp + 4) = v1;
        } else {
            float* ob = dst + ((size_t)(b * C_ + cc) * HW_ + r0) * HW_ + c0;
            for (int q = 0; q < 8; ++q)
                atomicAdd(ob + (ty0 + y) * HW_ + tx0 + ox + q, acc[k][q] * hy * hx[q]);
        }
    }
}

// ---------------------------------------------------------------------------
// Kernel 3a: gather overlap-add from ws patch buffer, divide by analytic w
// ---------------------------------------------------------------------------
__global__ __launch_bounds__(256) void gather_kernel(
    const float* __restrict__ ypatch, float* __restrict__ out)
{
    int idx = blockIdx.x * 256 + threadIdx.x;
    if (idx >= B_ * C_ * HW_ * HW_) return;
    int X = idx & 511;
    int Y = (idx >> 9) & 511;
    int bc = idx >> 18;
    int c = bc % 3, b = bc / 3;
    int nhA = Y >> 6, pyA = Y & 63;
    int nwA = X >> 6, pxA = X & 63;
    bool vA = nhA <= 6, vB = nhA >= 1;
    bool uA = nwA <= 6, uB = nwA >= 1;
    float hyA = hann128(pyA), hyB = hann128(pyA + 64);
    float hxA = hann128(pxA), hxB = hann128(pxA + 64);
    float wy = (vA ? hyA : 0.0f) + (vB ? hyB : 0.0f);
    float wx = (uA ? hxA : 0.0f) + (uB ? hxB : 0.0f);

    float acc = 0.0f;
    #pragma unroll
    for (int sy = 0; sy < 2; ++sy) {
        bool okY = sy == 0 ? vA : vB;
        int nh = sy == 0 ? nhA : nhA - 1;
        int py = sy == 0 ? pyA : pyA + 64;
        #pragma unroll
        for (int sx = 0; sx < 2; ++sx) {
            bool okX = sx == 0 ? uA : uB;
            int nw = sx == 0 ? nwA : nwA - 1;
            int px = sx == 0 ? pxA : pxA + 64;
            if (okY && okX) {
                size_t off = ((((size_t)b * NPOS_ + nh * 7 + nw) * C_ + c) << 14) + (py << 7) + px;
                acc += ypatch[off];
            }
        }
    }
    out[idx] = acc / (wy * wx + 1e-8f);
}

// ---------------------------------------------------------------------------
// Kernel 3b: in-place divide (atomic fallback path)
// ---------------------------------------------------------------------------
__global__ __launch_bounds__(256) void divide_kernel(float* __restrict__ out)
{
    int idx = blockIdx.x * 256 + threadIdx.x;
    if (idx >= B_ * C_ * HW_ * HW_) return;
    int X = idx & 511;
    int Y = (idx >> 9) & 511;
    int nhA = Y >> 6, pyA = Y & 63;
    int nwA = X >> 6, pxA = X & 63;
    float wy = (nhA <= 6 ? hann128(pyA) : 0.0f) + (nhA >= 1 ? hann128(pyA + 64) : 0.0f);
    float wx = (nwA <= 6 ? hann128(pxA) : 0.0f) + (nwA >= 1 ? hann128(pxA + 64) : 0.0f);
    out[idx] = out[idx] / (wy * wx + 1e-8f);
}

extern "C" void kernel_launch(void* const* d_in, const int* in_sizes, int n_in,
                              void* d_out, int out_size, void* d_ws, size_t ws_size,
                              hipStream_t stream)
{
    const float* x    = (const float*)d_in[0];
    const float* w1   = (const float*)d_in[1];
    const float* b1   = (const float*)d_in[2];
    const float* w2   = (const float*)d_in[3];
    const float* b2   = (const float*)d_in[4];
    const float* w3   = (const float*)d_in[5];
    const float* b3   = (const float*)d_in[6];
    const float* basis = (const float*)d_in[7];
    float* out = (float*)d_out;

    float* kf = (float*)d_ws;
    size_t kfBytes = ((size_t)NPOS_ * 961 * sizeof(float) + 255) & ~(size_t)255;
    size_t need = kfBytes + (size_t)BN_ * C_ * P_ * P_ * sizeof(float);

    psf_kernel<<<NPOS_, 256, 0, stream>>>(w1, b1, w2, b2, w3, b3, basis, kf);

    int nPix = B_ * C_ * HW_ * HW_;
    if (ws_size >= need) {
        float* ypatch = (float*)((char*)d_ws + kfBytes);
        conv_kernel<0><<<BN_ * C_ * 4, 256, 0, stream>>>(x, kf, ypatch);
        gather_kernel<<<(nPix + 255) / 256, 256, 0, stream>>>(ypatch, out);
    } else {
        hipMemsetAsync(d_out, 0, (size_t)out_size * sizeof(float), stream);
        conv_kernel<1><<<BN_ * C_ * 4, 256, 0, stream>>>(x, kf, out);
        divide_kernel<<<(nPix + 255) / 256, 256, 0, stream>>>(out);
    }
}

// Round 3
// 690.962 us; speedup vs baseline: 1.9786x; 1.7590x over previous
//
#include <hip/hip_runtime.h>
#include <math.h>

#define B_ 8
#define C_ 3
#define HW_ 512
#define P_ 128
#define S_ 64
#define K_ 31
#define NZ_ 15
#define HID_ 64
#define NPOS_ 49   // 7x7 patch positions
#define BN_ (B_*NPOS_)

#define INROWS_ 94          // 64 + 30 halo
#define INSTRIDE_ 100       // dwords; 16B-block rotation/row = 25 ≡ 1 (mod 8) -> conflict-free b128

__device__ __forceinline__ float hann128(int p) {
    return 0.5f - 0.5f * cosf(6.283185307179586f * (float)p / 128.0f);
}

// ---------------------------------------------------------------------------
// Kernel 1: MLP + pupil + 31x31 DFT -> flipped, normalized conv kernel kf
// ---------------------------------------------------------------------------
__global__ __launch_bounds__(256) void psf_kernel(
    const float* __restrict__ w1, const float* __restrict__ b1,
    const float* __restrict__ w2, const float* __restrict__ b2,
    const float* __restrict__ w3, const float* __restrict__ b3,
    const float* __restrict__ basis, float* __restrict__ kf_out)
{
    __shared__ float h1[HID_], h2[HID_], coef[NZ_];
    __shared__ float pupR[961], pupI[961], tR[961], tI[961];
    __shared__ float rootR[31], rootI[31];
    __shared__ float red[256];
    int n = blockIdx.x;
    int nh = n / 7, nw = n % 7;
    int tid = threadIdx.x;
    float cy = (float)(nh * S_ + P_ / 2) * (2.0f / (float)HW_) - 1.0f;
    float cx = (float)(nw * S_ + P_ / 2) * (2.0f / (float)HW_) - 1.0f;

    if (tid < HID_) h1[tid] = fmaxf(0.0f, cy * w1[tid] + cx * w1[HID_ + tid] + b1[tid]);
    if (tid < 31) {
        float ang = -6.283185307179586f * (float)tid / 31.0f;
        rootR[tid] = cosf(ang);
        rootI[tid] = sinf(ang);
    }
    __syncthreads();
    if (tid < HID_) {
        float s = b2[tid];
        for (int k = 0; k < HID_; ++k) s = fmaf(h1[k], w2[k * HID_ + tid], s);
        h2[tid] = fmaxf(0.0f, s);
    }
    __syncthreads();
    if (tid < NZ_) {
        float s = b3[tid];
        for (int k = 0; k < HID_; ++k) s = fmaf(h2[k], w3[k * NZ_ + tid], s);
        coef[tid] = s;
    }
    __syncthreads();

    for (int idx = tid; idx < 961; idx += 256) {
        int h = idx / 31, w = idx % 31;
        float ph = 0.0f;
        for (int z = 0; z < NZ_; ++z) ph = fmaf(coef[z], basis[z * 961 + idx], ph);
        int dh = h - 15, dw = w - 15;
        bool m = (dh * dh + dw * dw) <= 225;
        float sv, cv;
        sincosf(ph, &sv, &cv);
        pupR[idx] = m ? cv : 0.0f;
        pupI[idx] = m ? sv : 0.0f;
    }
    __syncthreads();

    for (int idx = tid; idx < 961; idx += 256) {
        int h = idx / 31, k = idx % 31;
        float ar = 0.0f, ai = 0.0f;
        for (int w = 0; w < 31; ++w) {
            int tt = (k * w) % 31;
            float cr = rootR[tt], ci = rootI[tt];
            float pr = pupR[h * 31 + w], pi = pupI[h * 31 + w];
            ar += pr * cr - pi * ci;
            ai += pr * ci + pi * cr;
        }
        tR[idx] = ar; tI[idx] = ai;
    }
    __syncthreads();

    float lsum = 0.0f;
    for (int idx = tid; idx < 961; idx += 256) {
        int u = idx / 31, k = idx % 31;
        float gr = 0.0f, gi = 0.0f;
        for (int h = 0; h < 31; ++h) {
            int tt = (u * h) % 31;
            float cr = rootR[tt], ci = rootI[tt];
            float ar = tR[h * 31 + k], ai = tI[h * 31 + k];
            gr += ar * cr - ai * ci;
            gi += ar * ci + ai * cr;
        }
        float p = gr * gr + gi * gi;
        pupR[idx] = p;
        lsum += p;
    }
    red[tid] = lsum;
    __syncthreads();
    for (int off = 128; off > 0; off >>= 1) {
        if (tid < off) red[tid] += red[tid + off];
        __syncthreads();
    }
    float inv = 1.0f / (red[0] + 1e-12f);
    // kf[j,i] = psf_un[(15-j)%31, (15-i)%31] * inv
    for (int idx = tid; idx < 961; idx += 256) {
        int j = idx / 31, i = idx % 31;
        int u = (15 - j + 31) % 31, v = (15 - i + 31) % 31;
        kf_out[n * 961 + idx] = pupR[u * 31 + v] * inv;
    }
}

// ---------------------------------------------------------------------------
// Kernel 2 (v3): per-patch depthwise 31x31 conv, windowed.
// grid: BN*C*4 blocks (2x2 tiles of 64x64), 256 threads.
// Thread strip = 2 rows (8 apart) x 8 cols. Lane map: ty = lane&7 (8 ADJACENT
// rows across consecutive lanes), tx = lane>>3. Row stride 100 dwords ->
// 16B-block rotation 1/row: any 8 consecutive lanes' b128 reads cover all 32
// banks exactly once (conflict-free). Kernel-row reads are wave-uniform
// broadcasts (free).
// ---------------------------------------------------------------------------
template<int MODE>
__global__ __launch_bounds__(256, 3) void conv_kernel(
    const float* __restrict__ x, const float* __restrict__ kf_all,
    float* __restrict__ dst)
{
    __shared__ float sIn[INROWS_ * INSTRIDE_];  // 94*100*4 = 37600 B
    __shared__ float sK[31 * 32];               // 3968 B

    int t = blockIdx.x;
    int tile = t & 3;
    int cc = (t >> 2) % 3;
    int bn = t / 12;
    int b = bn / NPOS_, n = bn % NPOS_;
    int nh = n / 7, nw = n % 7;
    int ty0 = (tile >> 1) * 64, tx0 = (tile & 1) * 64;
    int r0 = nh * S_, c0 = nw * S_;
    int tid = threadIdx.x;

    // kernel -> LDS, rows padded to 32
    for (int i = tid; i < 31 * 32; i += 256) {
        int j = i >> 5, q = i & 31;
        sK[i] = (q < 31) ? kf_all[n * 961 + j * 31 + q] : 0.0f;
    }
    // input tile (zero-padded patch semantics) -> LDS, 94 rows x 96 cols used
    const float* xb = x + ((size_t)(b * C_ + cc) * HW_ + r0) * HW_ + c0;
    for (int i = tid; i < INROWS_ * 96; i += 256) {
        int r = i / 96, c = i % 96;
        int pr = ty0 - 15 + r, pc = tx0 - 15 + c;
        float v = 0.0f;
        if (pr >= 0 && pr < P_ && pc >= 0 && pc < P_) v = xb[pr * HW_ + pc];
        sIn[r * INSTRIDE_ + c] = v;
    }
    __syncthreads();

    int lane = tid & 63, w = tid >> 6;
    int ty = lane & 7, tx = lane >> 3;   // consecutive lanes -> consecutive rows
    int ox = tx * 8;
    // output rows: y(k) = w*16 + ty + 8*k, k = 0,1
    float acc[2][8] = {};

    #pragma unroll 1
    for (int j = 0; j < 31; ++j) {
        float kr[32];
        float4* krv = (float4*)kr;
        #pragma unroll
        for (int q = 0; q < 8; ++q) krv[q] = *(const float4*)&sK[j * 32 + q * 4];
        #pragma unroll
        for (int k = 0; k < 2; ++k) {
            int r = w * 16 + ty + 8 * k + j;        // sIn row = y + j
            const float* rp = &sIn[r * INSTRIDE_ + ox];
            float xv[40];
            float4* xvv = (float4*)xv;
            #pragma unroll
            for (int q = 0; q < 10; ++q) xvv[q] = *(const float4*)&rp[q * 4];
            #pragma unroll
            for (int i = 0; i < 31; ++i) {
                float kv = kr[i];
                #pragma unroll
                for (int q = 0; q < 8; ++q)
                    acc[k][q] = fmaf(kv, xv[i + q], acc[k][q]);
            }
        }
    }

    float hx[8];
    #pragma unroll
    for (int q = 0; q < 8; ++q) hx[q] = hann128(tx0 + ox + q);

    #pragma unroll
    for (int k = 0; k < 2; ++k) {
        int y = w * 16 + ty + 8 * k;
        float hy = hann128(ty0 + y);
        if (MODE == 0) {
            float* yp = dst + (((size_t)bn * C_ + cc) << 14) + (ty0 + y) * P_ + tx0 + ox;
            float4 v0, v1;
            v0.x = acc[k][0] * hy * hx[0]; v0.y = acc[k][1] * hy * hx[1];
            v0.z = acc[k][2] * hy * hx[2]; v0.w = acc[k][3] * hy * hx[3];
            v1.x = acc[k][4] * hy * hx[4]; v1.y = acc[k][5] * hy * hx[5];
            v1.z = acc[k][6] * hy * hx[6]; v1.w = acc[k][7] * hy * hx[7];
            *(float4*)yp = v0;
            *(float4*)(yp + 4) = v1;
        } else {
            float* ob = dst + ((size_t)(b * C_ + cc) * HW_ + r0) * HW_ + c0;
            for (int q = 0; q < 8; ++q)
                atomicAdd(ob + (ty0 + y) * HW_ + tx0 + ox + q, acc[k][q] * hy * hx[q]);
        }
    }
}

// ---------------------------------------------------------------------------
// Kernel 3a: gather overlap-add from ws patch buffer, divide by analytic w
// ---------------------------------------------------------------------------
__global__ __launch_bounds__(256) void gather_kernel(
    const float* __restrict__ ypatch, float* __restrict__ out)
{
    int idx = blockIdx.x * 256 + threadIdx.x;
    if (idx >= B_ * C_ * HW_ * HW_) return;
    int X = idx & 511;
    int Y = (idx >> 9) & 511;
    int bc = idx >> 18;
    int c = bc % 3, b = bc / 3;
    int nhA = Y >> 6, pyA = Y & 63;
    int nwA = X >> 6, pxA = X & 63;
    bool vA = nhA <= 6, vB = nhA >= 1;
    bool uA = nwA <= 6, uB = nwA >= 1;
    float hyA = hann128(pyA), hyB = hann128(pyA + 64);
    float hxA = hann128(pxA), hxB = hann128(pxA + 64);
    float wy = (vA ? hyA : 0.0f) + (vB ? hyB : 0.0f);
    float wx = (uA ? hxA : 0.0f) + (uB ? hxB : 0.0f);

    float acc = 0.0f;
    #pragma unroll
    for (int sy = 0; sy < 2; ++sy) {
        bool okY = sy == 0 ? vA : vB;
        int nh = sy == 0 ? nhA : nhA - 1;
        int py = sy == 0 ? pyA : pyA + 64;
        #pragma unroll
        for (int sx = 0; sx < 2; ++sx) {
            bool okX = sx == 0 ? uA : uB;
            int nw = sx == 0 ? nwA : nwA - 1;
            int px = sx == 0 ? pxA : pxA + 64;
            if (okY && okX) {
                size_t off = ((((size_t)b * NPOS_ + nh * 7 + nw) * C_ + c) << 14) + (py << 7) + px;
                acc += ypatch[off];
            }
        }
    }
    out[idx] = acc / (wy * wx + 1e-8f);
}

// ---------------------------------------------------------------------------
// Kernel 3b: in-place divide (atomic fallback path)
// ---------------------------------------------------------------------------
__global__ __launch_bounds__(256) void divide_kernel(float* __restrict__ out)
{
    int idx = blockIdx.x * 256 + threadIdx.x;
    if (idx >= B_ * C_ * HW_ * HW_) return;
    int X = idx & 511;
    int Y = (idx >> 9) & 511;
    int nhA = Y >> 6, pyA = Y & 63;
    int nwA = X >> 6, pxA = X & 63;
    float wy = (nhA <= 6 ? hann128(pyA) : 0.0f) + (nhA >= 1 ? hann128(pyA + 64) : 0.0f);
    float wx = (nwA <= 6 ? hann128(pxA) : 0.0f) + (nwA >= 1 ? hann128(pxA + 64) : 0.0f);
    out[idx] = out[idx] / (wy * wx + 1e-8f);
}

extern "C" void kernel_launch(void* const* d_in, const int* in_sizes, int n_in,
                              void* d_out, int out_size, void* d_ws, size_t ws_size,
                              hipStream_t stream)
{
    const float* x    = (const float*)d_in[0];
    const float* w1   = (const float*)d_in[1];
    const float* b1   = (const float*)d_in[2];
    const float* w2   = (const float*)d_in[3];
    const float* b2   = (const float*)d_in[4];
    const float* w3   = (const float*)d_in[5];
    const float* b3   = (const float*)d_in[6];
    const float* basis = (const float*)d_in[7];
    float* out = (float*)d_out;

    float* kf = (float*)d_ws;
    size_t kfBytes = ((size_t)NPOS_ * 961 * sizeof(float) + 255) & ~(size_t)255;
    size_t need = kfBytes + (size_t)BN_ * C_ * P_ * P_ * sizeof(float);

    psf_kernel<<<NPOS_, 256, 0, stream>>>(w1, b1, w2, b2, w3, b3, basis, kf);

    int nPix = B_ * C_ * HW_ * HW_;
    if (ws_size >= need) {
        float* ypatch = (float*)((char*)d_ws + kfBytes);
        conv_kernel<0><<<BN_ * C_ * 4, 256, 0, stream>>>(x, kf, ypatch);
        gather_kernel<<<(nPix + 255) / 256, 256, 0, stream>>>(ypatch, out);
    } else {
        hipMemsetAsync(d_out, 0, (size_t)out_size * sizeof(float), stream);
        conv_kernel<1><<<BN_ * C_ * 4, 256, 0, stream>>>(x, kf, out);
        divide_kernel<<<(nPix + 255) / 256, 256, 0, stream>>>(out);
    }
}

// Round 4
// 137.883 us; speedup vs baseline: 9.9150x; 5.0112x over previous
//
#include <hip/hip_runtime.h>
#include <math.h>

#define B_ 8
#define C_ 3
#define HW_ 512
#define P_ 128
#define S_ 64
#define K_ 31
#define NZ_ 15
#define HID_ 64
#define NPOS_ 49   // 7x7 patch positions
#define BN_ (B_*NPOS_)

#define LSTRIDE_ 104   // bf16 elems/row; 208 B = 13 x 16B blocks (odd -> conflict-free b128)
#define FRAG_U32_ 256  // one B fragment = 64 lanes x 16 B = 256 uints
#define NFRAG_ 62      // 31 j x 2 chunks
#define BPOS_U32_ (NFRAG_ * FRAG_U32_)  // 15872 uints per patch position

typedef __attribute__((ext_vector_type(8))) short bf16x8;
typedef __attribute__((ext_vector_type(4))) float f32x4;

__device__ __forceinline__ float hann128(int p) {
    return 0.5f - 0.5f * cosf(6.283185307179586f * (float)p / 128.0f);
}

__device__ __forceinline__ unsigned short bf16_rne(float f) {
    union { float f; unsigned int u; } v; v.f = f;
    unsigned int r = v.u + 0x7fffu + ((v.u >> 16) & 1u);
    return (unsigned short)(r >> 16);
}

// ---------------------------------------------------------------------------
// Kernel 1: MLP + pupil + 31x31 DFT -> normalized flipped kernel -> B-fragment
// precompute (banded Toeplitz, MFMA fragment order). One block per position.
// ---------------------------------------------------------------------------
__global__ __launch_bounds__(256) void psf_kernel(
    const float* __restrict__ w1, const float* __restrict__ b1,
    const float* __restrict__ w2, const float* __restrict__ b2,
    const float* __restrict__ w3, const float* __restrict__ b3,
    const float* __restrict__ basis, unsigned int* __restrict__ bfrags)
{
    __shared__ float h1[HID_], h2[HID_], coef[NZ_];
    __shared__ float pupR[961], pupI[961], tR[961], tI[961];
    __shared__ float rootR[31], rootI[31];
    __shared__ float red[256];
    int n = blockIdx.x;
    int nh = n / 7, nw = n % 7;
    int tid = threadIdx.x;
    float cy = (float)(nh * S_ + P_ / 2) * (2.0f / (float)HW_) - 1.0f;
    float cx = (float)(nw * S_ + P_ / 2) * (2.0f / (float)HW_) - 1.0f;

    if (tid < HID_) h1[tid] = fmaxf(0.0f, cy * w1[tid] + cx * w1[HID_ + tid] + b1[tid]);
    if (tid < 31) {
        float ang = -6.283185307179586f * (float)tid / 31.0f;
        rootR[tid] = cosf(ang);
        rootI[tid] = sinf(ang);
    }
    __syncthreads();
    if (tid < HID_) {
        float s = b2[tid];
        for (int k = 0; k < HID_; ++k) s = fmaf(h1[k], w2[k * HID_ + tid], s);
        h2[tid] = fmaxf(0.0f, s);
    }
    __syncthreads();
    if (tid < NZ_) {
        float s = b3[tid];
        for (int k = 0; k < HID_; ++k) s = fmaf(h2[k], w3[k * NZ_ + tid], s);
        coef[tid] = s;
    }
    __syncthreads();

    for (int idx = tid; idx < 961; idx += 256) {
        int h = idx / 31, w = idx % 31;
        float ph = 0.0f;
        for (int z = 0; z < NZ_; ++z) ph = fmaf(coef[z], basis[z * 961 + idx], ph);
        int dh = h - 15, dw = w - 15;
        bool m = (dh * dh + dw * dw) <= 225;
        float sv, cv;
        sincosf(ph, &sv, &cv);
        pupR[idx] = m ? cv : 0.0f;
        pupI[idx] = m ? sv : 0.0f;
    }
    __syncthreads();

    for (int idx = tid; idx < 961; idx += 256) {
        int h = idx / 31, k = idx % 31;
        float ar = 0.0f, ai = 0.0f;
        for (int w = 0; w < 31; ++w) {
            int tt = (k * w) % 31;
            float cr = rootR[tt], ci = rootI[tt];
            float pr = pupR[h * 31 + w], pi = pupI[h * 31 + w];
            ar += pr * cr - pi * ci;
            ai += pr * ci + pi * cr;
        }
        tR[idx] = ar; tI[idx] = ai;
    }
    __syncthreads();

    float lsum = 0.0f;
    for (int idx = tid; idx < 961; idx += 256) {
        int u = idx / 31, k = idx % 31;
        float gr = 0.0f, gi = 0.0f;
        for (int h = 0; h < 31; ++h) {
            int tt = (u * h) % 31;
            float cr = rootR[tt], ci = rootI[tt];
            float ar = tR[h * 31 + k], ai = tI[h * 31 + k];
            gr += ar * cr - ai * ci;
            gi += ar * ci + ai * cr;
        }
        float p = gr * gr + gi * gi;
        pupR[idx] = p;
        lsum += p;
    }
    red[tid] = lsum;
    __syncthreads();
    for (int off = 128; off > 0; off >>= 1) {
        if (tid < off) red[tid] += red[tid + off];
        __syncthreads();
    }
    float inv = 1.0f / (red[0] + 1e-12f);
    // kf[j,i] = psf_un[(15-j)%31, (15-i)%31] * inv  -> stash in tR (free now)
    for (int idx = tid; idx < 961; idx += 256) {
        int j = idx / 31, i = idx % 31;
        int u = (15 - j + 31) % 31, v = (15 - i + 31) % 31;
        tR[idx] = pupR[u * 31 + v] * inv;
    }
    __syncthreads();

    // B fragments: frag (j,c), lane l: col n = l&15, k = (l>>4)*8 + e (e=0..7)
    // B_c[k,n] = kf[j, 16c + (k-n)] if 0 <= k-n < 16 and 16c+(k-n) < 31 else 0
    unsigned int* bf = bfrags + (size_t)n * BPOS_U32_;
    for (int w2 = tid; w2 < BPOS_U32_; w2 += 256) {
        int jc = w2 >> 8;           // 256 uints per fragment
        int j = jc >> 1, c = jc & 1;
        int rem = w2 & 255;
        int l = rem >> 2, ew = rem & 3;
        int nn = l & 15, kg = l >> 4;
        unsigned int pack = 0;
        #pragma unroll
        for (int q = 0; q < 2; ++q) {
            int e = ew * 2 + q;
            int kk = kg * 8 + e;
            int ii = kk - nn;
            int tap = 16 * c + ii;
            float v = (ii >= 0 && ii < 16 && tap < 31) ? tR[j * 31 + tap] : 0.0f;
            pack |= (unsigned int)bf16_rne(v) << (16 * q);
        }
        bf[w2] = pack;
    }
}

// ---------------------------------------------------------------------------
// Kernel 2 (v4): depthwise 31x31 conv as banded bf16 MFMA GEMM.
// Block = 64x64 output tile of one (patch, channel). 4 waves, each a 16-row
// strip with 4 accumulators (16x16 C-tiles). Per j: 5 ds_read_b128 A-window
// fragments + 2 coalesced global B-fragment loads + 8 mfma_f32_16x16x32_bf16.
// ---------------------------------------------------------------------------
template<int MODE>
__global__ __launch_bounds__(256) void conv_mfma_kernel(
    const float* __restrict__ x, const unsigned int* __restrict__ bfrags,
    float* __restrict__ dst)
{
    __shared__ unsigned short sIn[94 * LSTRIDE_];   // 19552 B bf16 tile

    int t = blockIdx.x;
    int tile = t & 3;
    int cc = (t >> 2) % 3;
    int bn = t / 12;
    int b = bn / NPOS_, n = bn % NPOS_;
    int nh = n / 7, nw = n % 7;
    int ty0 = (tile >> 1) * 64, tx0 = (tile & 1) * 64;
    int r0 = nh * S_, c0 = nw * S_;
    int tid = threadIdx.x;

    // stage input patch-tile (zero-padded) as bf16: rows 0..93, cols 0..95
    const float* xb = x + ((size_t)(b * C_ + cc) * HW_ + r0) * HW_ + c0;
    for (int i = tid; i < 94 * 48; i += 256) {
        int r = i / 48, c2 = (i % 48) * 2;
        int pr = ty0 - 15 + r;
        unsigned int pack = 0;
        #pragma unroll
        for (int q = 0; q < 2; ++q) {
            int pc = tx0 - 15 + c2 + q;
            float v = 0.0f;
            if (pr >= 0 && pr < P_ && pc >= 0 && pc < P_ && (c2 + q) < 94)
                v = xb[pr * HW_ + pc];
            pack |= (unsigned int)bf16_rne(v) << (16 * q);
        }
        *(unsigned int*)&sIn[r * LSTRIDE_ + c2] = pack;
    }
    __syncthreads();

    int lane = tid & 63, wv = tid >> 6;
    int m0 = wv * 16;
    int lrow = lane & 15, lkg = lane >> 4;

    f32x4 acc0 = {0.f, 0.f, 0.f, 0.f};
    f32x4 acc1 = {0.f, 0.f, 0.f, 0.f};
    f32x4 acc2 = {0.f, 0.f, 0.f, 0.f};
    f32x4 acc3 = {0.f, 0.f, 0.f, 0.f};

    // A byte offset: row (m0 + lrow + j) * 208 + window*32 + lkg*16
    int aoff = (m0 + lrow) * (LSTRIDE_ * 2) + lkg * 16;
    const bf16x8* bbase = (const bf16x8*)(bfrags + (size_t)n * BPOS_U32_) + lane;

    #pragma unroll 1
    for (int j = 0; j < 31; ++j) {
        const char* ap = (const char*)sIn + aoff;
        bf16x8 A0 = *(const bf16x8*)(ap);
        bf16x8 A1 = *(const bf16x8*)(ap + 32);
        bf16x8 A2 = *(const bf16x8*)(ap + 64);
        bf16x8 A3 = *(const bf16x8*)(ap + 96);
        bf16x8 A4 = *(const bf16x8*)(ap + 128);
        bf16x8 B0 = bbase[j * 128];
        bf16x8 B1 = bbase[j * 128 + 64];
        acc0 = __builtin_amdgcn_mfma_f32_16x16x32_bf16(A0, B0, acc0, 0, 0, 0);
        acc1 = __builtin_amdgcn_mfma_f32_16x16x32_bf16(A1, B0, acc1, 0, 0, 0);
        acc2 = __builtin_amdgcn_mfma_f32_16x16x32_bf16(A2, B0, acc2, 0, 0, 0);
        acc3 = __builtin_amdgcn_mfma_f32_16x16x32_bf16(A3, B0, acc3, 0, 0, 0);
        acc0 = __builtin_amdgcn_mfma_f32_16x16x32_bf16(A1, B1, acc0, 0, 0, 0);
        acc1 = __builtin_amdgcn_mfma_f32_16x16x32_bf16(A2, B1, acc1, 0, 0, 0);
        acc2 = __builtin_amdgcn_mfma_f32_16x16x32_bf16(A3, B1, acc2, 0, 0, 0);
        acc3 = __builtin_amdgcn_mfma_f32_16x16x32_bf16(A4, B1, acc3, 0, 0, 0);
        aoff += LSTRIDE_ * 2;
    }

    // epilogue: C/D layout col = lane&15, row = lkg*4 + r (m89-verified)
    float hy[4];
    #pragma unroll
    for (int r = 0; r < 4; ++r) hy[r] = hann128(ty0 + m0 + lkg * 4 + r);

    #pragma unroll
    for (int xt = 0; xt < 4; ++xt) {
        f32x4 a = (xt == 0) ? acc0 : (xt == 1) ? acc1 : (xt == 2) ? acc2 : acc3;
        int xloc = tx0 + 16 * xt + lrow;
        float hxv = hann128(xloc);
        #pragma unroll
        for (int r = 0; r < 4; ++r) {
            int yloc = ty0 + m0 + lkg * 4 + r;
            float val = a[r] * hy[r] * hxv;
            if (MODE == 0) {
                dst[(((size_t)bn * C_ + cc) << 14) + yloc * P_ + xloc] = val;
            } else {
                atomicAdd(dst + ((size_t)(b * C_ + cc) * HW_ + r0 + yloc) * HW_ + c0 + xloc, val);
            }
        }
    }
}

// ---------------------------------------------------------------------------
// Kernel 3a: gather overlap-add from ws patch buffer, divide by analytic w
// ---------------------------------------------------------------------------
__global__ __launch_bounds__(256) void gather_kernel(
    const float* __restrict__ ypatch, float* __restrict__ out)
{
    int idx = blockIdx.x * 256 + threadIdx.x;
    if (idx >= B_ * C_ * HW_ * HW_) return;
    int X = idx & 511;
    int Y = (idx >> 9) & 511;
    int bc = idx >> 18;
    int c = bc % 3, b = bc / 3;
    int nhA = Y >> 6, pyA = Y & 63;
    int nwA = X >> 6, pxA = X & 63;
    bool vA = nhA <= 6, vB = nhA >= 1;
    bool uA = nwA <= 6, uB = nwA >= 1;
    float hyA = hann128(pyA), hyB = hann128(pyA + 64);
    float hxA = hann128(pxA), hxB = hann128(pxA + 64);
    float wy = (vA ? hyA : 0.0f) + (vB ? hyB : 0.0f);
    float wx = (uA ? hxA : 0.0f) + (uB ? hxB : 0.0f);

    float acc = 0.0f;
    #pragma unroll
    for (int sy = 0; sy < 2; ++sy) {
        bool okY = sy == 0 ? vA : vB;
        int nh = sy == 0 ? nhA : nhA - 1;
        int py = sy == 0 ? pyA : pyA + 64;
        #pragma unroll
        for (int sx = 0; sx < 2; ++sx) {
            bool okX = sx == 0 ? uA : uB;
            int nw = sx == 0 ? nwA : nwA - 1;
            int px = sx == 0 ? pxA : pxA + 64;
            if (okY && okX) {
                size_t off = ((((size_t)b * NPOS_ + nh * 7 + nw) * C_ + c) << 14) + (py << 7) + px;
                acc += ypatch[off];
            }
        }
    }
    out[idx] = acc / (wy * wx + 1e-8f);
}

// ---------------------------------------------------------------------------
// Kernel 3b: in-place divide (atomic fallback path)
// ---------------------------------------------------------------------------
__global__ __launch_bounds__(256) void divide_kernel(float* __restrict__ out)
{
    int idx = blockIdx.x * 256 + threadIdx.x;
    if (idx >= B_ * C_ * HW_ * HW_) return;
    int X = idx & 511;
    int Y = (idx >> 9) & 511;
    int nhA = Y >> 6, pyA = Y & 63;
    int nwA = X >> 6, pxA = X & 63;
    float wy = (nhA <= 6 ? hann128(pyA) : 0.0f) + (nhA >= 1 ? hann128(pyA + 64) : 0.0f);
    float wx = (nwA <= 6 ? hann128(pxA) : 0.0f) + (nwA >= 1 ? hann128(pxA + 64) : 0.0f);
    out[idx] = out[idx] / (wy * wx + 1e-8f);
}

extern "C" void kernel_launch(void* const* d_in, const int* in_sizes, int n_in,
                              void* d_out, int out_size, void* d_ws, size_t ws_size,
                              hipStream_t stream)
{
    const float* x    = (const float*)d_in[0];
    const float* w1   = (const float*)d_in[1];
    const float* b1   = (const float*)d_in[2];
    const float* w2   = (const float*)d_in[3];
    const float* b2   = (const float*)d_in[4];
    const float* w3   = (const float*)d_in[5];
    const float* b3   = (const float*)d_in[6];
    const float* basis = (const float*)d_in[7];
    float* out = (float*)d_out;

    unsigned int* bfrags = (unsigned int*)d_ws;
    size_t bfBytes = (size_t)NPOS_ * BPOS_U32_ * sizeof(unsigned int);   // ~3.11 MB
    size_t need = bfBytes + (size_t)BN_ * C_ * P_ * P_ * sizeof(float);  // + 77 MB

    psf_kernel<<<NPOS_, 256, 0, stream>>>(w1, b1, w2, b2, w3, b3, basis, bfrags);

    int nPix = B_ * C_ * HW_ * HW_;
    if (ws_size >= need) {
        float* ypatch = (float*)((char*)d_ws + bfBytes);
        conv_mfma_kernel<0><<<BN_ * C_ * 4, 256, 0, stream>>>(x, bfrags, ypatch);
        gather_kernel<<<(nPix + 255) / 256, 256, 0, stream>>>(ypatch, out);
    } else {
        hipMemsetAsync(d_out, 0, (size_t)out_size * sizeof(float), stream);
        conv_mfma_kernel<1><<<BN_ * C_ * 4, 256, 0, stream>>>(x, bfrags, out);
        divide_kernel<<<(nPix + 255) / 256, 256, 0, stream>>>(out);
    }
}

// Round 5
// 125.155 us; speedup vs baseline: 10.9234x; 1.1017x over previous
//
#include <hip/hip_runtime.h>
#include <math.h>

#define B_ 8
#define C_ 3
#define HW_ 512
#define P_ 128
#define S_ 64
#define K_ 31
#define NZ_ 15
#define HID_ 64
#define NPOS_ 49   // 7x7 patch positions
#define BN_ (B_*NPOS_)

#define LSTRIDE_ 168   // bf16 elems/row; 336 B = 21 x 16B blocks (odd -> conflict-free b128)
#define TROWS_ 158     // 128 + 30 halo
#define TCOLS_ 160     // 128 + 31 halo + 1 (cols 158,159 always zero / band-masked)
#define FRAG_U32_ 256  // one B fragment = 64 lanes x 16 B = 256 uints
#define NFRAG_ 62      // 31 j x 2 chunks
#define BPOS_U32_ (NFRAG_ * FRAG_U32_)  // 15872 uints per patch position

typedef __attribute__((ext_vector_type(8))) short bf16x8;
typedef __attribute__((ext_vector_type(4))) float f32x4;

__device__ __forceinline__ float hann128(int p) {
    return 0.5f - 0.5f * cosf(6.283185307179586f * (float)p / 128.0f);
}

__device__ __forceinline__ unsigned short bf16_rne(float f) {
    union { float f; unsigned int u; } v; v.f = f;
    unsigned int r = v.u + 0x7fffu + ((v.u >> 16) & 1u);
    return (unsigned short)(r >> 16);
}

// ---------------------------------------------------------------------------
// Kernel 1: MLP + pupil + 31x31 DFT -> normalized flipped kernel -> B-fragment
// precompute (banded Toeplitz, MFMA fragment order). One block per position.
// ---------------------------------------------------------------------------
__global__ __launch_bounds__(256) void psf_kernel(
    const float* __restrict__ w1, const float* __restrict__ b1,
    const float* __restrict__ w2, const float* __restrict__ b2,
    const float* __restrict__ w3, const float* __restrict__ b3,
    const float* __restrict__ basis, unsigned int* __restrict__ bfrags)
{
    __shared__ float h1[HID_], h2[HID_], coef[NZ_];
    __shared__ float pupR[961], pupI[961], tR[961], tI[961];
    __shared__ float rootR[31], rootI[31];
    __shared__ float red[256];
    int n = blockIdx.x;
    int nh = n / 7, nw = n % 7;
    int tid = threadIdx.x;
    float cy = (float)(nh * S_ + P_ / 2) * (2.0f / (float)HW_) - 1.0f;
    float cx = (float)(nw * S_ + P_ / 2) * (2.0f / (float)HW_) - 1.0f;

    if (tid < HID_) h1[tid] = fmaxf(0.0f, cy * w1[tid] + cx * w1[HID_ + tid] + b1[tid]);
    if (tid < 31) {
        float ang = -6.283185307179586f * (float)tid / 31.0f;
        rootR[tid] = cosf(ang);
        rootI[tid] = sinf(ang);
    }
    __syncthreads();
    if (tid < HID_) {
        float s = b2[tid];
        for (int k = 0; k < HID_; ++k) s = fmaf(h1[k], w2[k * HID_ + tid], s);
        h2[tid] = fmaxf(0.0f, s);
    }
    __syncthreads();
    if (tid < NZ_) {
        float s = b3[tid];
        for (int k = 0; k < HID_; ++k) s = fmaf(h2[k], w3[k * NZ_ + tid], s);
        coef[tid] = s;
    }
    __syncthreads();

    for (int idx = tid; idx < 961; idx += 256) {
        int h = idx / 31, w = idx % 31;
        float ph = 0.0f;
        for (int z = 0; z < NZ_; ++z) ph = fmaf(coef[z], basis[z * 961 + idx], ph);
        int dh = h - 15, dw = w - 15;
        bool m = (dh * dh + dw * dw) <= 225;
        float sv, cv;
        sincosf(ph, &sv, &cv);
        pupR[idx] = m ? cv : 0.0f;
        pupI[idx] = m ? sv : 0.0f;
    }
    __syncthreads();

    for (int idx = tid; idx < 961; idx += 256) {
        int h = idx / 31, k = idx % 31;
        float ar = 0.0f, ai = 0.0f;
        for (int w = 0; w < 31; ++w) {
            int tt = (k * w) % 31;
            float cr = rootR[tt], ci = rootI[tt];
            float pr = pupR[h * 31 + w], pi = pupI[h * 31 + w];
            ar += pr * cr - pi * ci;
            ai += pr * ci + pi * cr;
        }
        tR[idx] = ar; tI[idx] = ai;
    }
    __syncthreads();

    float lsum = 0.0f;
    for (int idx = tid; idx < 961; idx += 256) {
        int u = idx / 31, k = idx % 31;
        float gr = 0.0f, gi = 0.0f;
        for (int h = 0; h < 31; ++h) {
            int tt = (u * h) % 31;
            float cr = rootR[tt], ci = rootI[tt];
            float ar = tR[h * 31 + k], ai = tI[h * 31 + k];
            gr += ar * cr - ai * ci;
            gi += ar * ci + ai * cr;
        }
        float p = gr * gr + gi * gi;
        pupR[idx] = p;
        lsum += p;
    }
    red[tid] = lsum;
    __syncthreads();
    for (int off = 128; off > 0; off >>= 1) {
        if (tid < off) red[tid] += red[tid + off];
        __syncthreads();
    }
    float inv = 1.0f / (red[0] + 1e-12f);
    // kf[j,i] = psf_un[(15-j)%31, (15-i)%31] * inv  -> stash in tR (free now)
    for (int idx = tid; idx < 961; idx += 256) {
        int j = idx / 31, i = idx % 31;
        int u = (15 - j + 31) % 31, v = (15 - i + 31) % 31;
        tR[idx] = pupR[u * 31 + v] * inv;
    }
    __syncthreads();

    // B fragments: frag (j,c), lane l: col n = l&15, k = (l>>4)*8 + e (e=0..7)
    // B_c[k,n] = kf[j, 16c + (k-n)] if 0 <= k-n < 16 and 16c+(k-n) < 31 else 0
    unsigned int* bf = bfrags + (size_t)n * BPOS_U32_;
    for (int w2 = tid; w2 < BPOS_U32_; w2 += 256) {
        int jc = w2 >> 8;           // 256 uints per fragment
        int j = jc >> 1, c = jc & 1;
        int rem = w2 & 255;
        int l = rem >> 2, ew = rem & 3;
        int nn = l & 15, kg = l >> 4;
        unsigned int pack = 0;
        #pragma unroll
        for (int q = 0; q < 2; ++q) {
            int e = ew * 2 + q;
            int kk = kg * 8 + e;
            int ii = kk - nn;
            int tap = 16 * c + ii;
            float v = (ii >= 0 && ii < 16 && tap < 31) ? tR[j * 31 + tap] : 0.0f;
            pack |= (unsigned int)bf16_rne(v) << (16 * q);
        }
        bf[w2] = pack;
    }
}

// ---------------------------------------------------------------------------
// Kernel 2 (v5): depthwise 31x31 conv as banded bf16 MFMA GEMM.
// ONE block per (patch, channel): 128x128 output, 512 threads = 8 waves, each
// wave a 16-row strip x 128 cols. Per j: 9 ds_read_b128 A-windows (shared by
// adjacent 16-col chunks) + 2 global B-fragment loads (L1-reused by 8 waves)
// + 16 mfma_f32_16x16x32_bf16.
// ---------------------------------------------------------------------------
template<int MODE>
__global__ __launch_bounds__(512) void conv_mfma_kernel(
    const float* __restrict__ x, const unsigned int* __restrict__ bfrags,
    float* __restrict__ dst)
{
    __shared__ unsigned short sIn[TROWS_ * LSTRIDE_];   // 158*168*2 = 53088 B

    int t = blockIdx.x;
    int cc = t % 3;
    int bn = t / 3;
    int b = bn / NPOS_, n = bn % NPOS_;
    int nh = n / 7, nw = n % 7;
    int r0 = nh * S_, c0 = nw * S_;
    int tid = threadIdx.x;

    // stage full patch tile (zero-padded) as bf16: rows 0..157, cols 0..159
    // tile[r,c] = x[r0 + r-15, c0 + c-15] if 15 <= r,c < 143 else 0
    const float* xb = x + ((size_t)(b * C_ + cc) * HW_ + r0) * HW_ + c0;
    for (int i = tid; i < TROWS_ * (TCOLS_ / 2); i += 512) {
        int r = i / (TCOLS_ / 2), cu = i % (TCOLS_ / 2);
        int c2 = cu * 2;
        bool rv = (r >= 15 && r < 143);
        unsigned int pack = 0;
        #pragma unroll
        for (int q = 0; q < 2; ++q) {
            int c = c2 + q;
            float v = 0.0f;
            if (rv && c >= 15 && c < 143) v = xb[(r - 15) * HW_ + (c - 15)];
            pack |= (unsigned int)bf16_rne(v) << (16 * q);
        }
        *(unsigned int*)&sIn[r * LSTRIDE_ + c2] = pack;
    }
    __syncthreads();

    int lane = tid & 63, wv = tid >> 6;
    int m0 = wv * 16;
    int lrow = lane & 15, lkg = lane >> 4;

    f32x4 acc[8];
    #pragma unroll
    for (int c = 0; c < 8; ++c) acc[c] = (f32x4){0.f, 0.f, 0.f, 0.f};

    int abase = (m0 + lrow) * (LSTRIDE_ * 2) + lkg * 16;   // byte offset, + j*row each iter
    const bf16x8* bbase = (const bf16x8*)(bfrags + (size_t)n * BPOS_U32_) + lane;

    #pragma unroll 1
    for (int j = 0; j < 31; ++j) {
        const char* ap = (const char*)sIn + abase;
        bf16x8 A[9];
        #pragma unroll
        for (int p = 0; p < 9; ++p) A[p] = *(const bf16x8*)(ap + p * 32);
        bf16x8 B0 = bbase[j * 128];
        bf16x8 B1 = bbase[j * 128 + 64];
        #pragma unroll
        for (int c = 0; c < 8; ++c) {
            acc[c] = __builtin_amdgcn_mfma_f32_16x16x32_bf16(A[c], B0, acc[c], 0, 0, 0);
            acc[c] = __builtin_amdgcn_mfma_f32_16x16x32_bf16(A[c + 1], B1, acc[c], 0, 0, 0);
        }
        abase += LSTRIDE_ * 2;
    }

    // epilogue: C/D layout col = lane&15, row = lkg*4 + r (m89-verified)
    float hy[4];
    #pragma unroll
    for (int r = 0; r < 4; ++r) hy[r] = hann128(m0 + lkg * 4 + r);

    #pragma unroll
    for (int c = 0; c < 8; ++c) {
        int xloc = 16 * c + lrow;
        float hxv = hann128(xloc);
        #pragma unroll
        for (int r = 0; r < 4; ++r) {
            int yloc = m0 + lkg * 4 + r;
            float val = acc[c][r] * hy[r] * hxv;
            if (MODE == 0) {
                dst[(((size_t)bn * C_ + cc) << 14) + yloc * P_ + xloc] = val;
            } else {
                atomicAdd(dst + ((size_t)(b * C_ + cc) * HW_ + r0 + yloc) * HW_ + c0 + xloc, val);
            }
        }
    }
}

// ---------------------------------------------------------------------------
// Kernel 3a: gather overlap-add from ws patch buffer, divide by analytic w
// ---------------------------------------------------------------------------
__global__ __launch_bounds__(256) void gather_kernel(
    const float* __restrict__ ypatch, float* __restrict__ out)
{
    int idx = blockIdx.x * 256 + threadIdx.x;
    if (idx >= B_ * C_ * HW_ * HW_) return;
    int X = idx & 511;
    int Y = (idx >> 9) & 511;
    int bc = idx >> 18;
    int c = bc % 3, b = bc / 3;
    int nhA = Y >> 6, pyA = Y & 63;
    int nwA = X >> 6, pxA = X & 63;
    bool vA = nhA <= 6, vB = nhA >= 1;
    bool uA = nwA <= 6, uB = nwA >= 1;
    float hyA = hann128(pyA), hyB = hann128(pyA + 64);
    float hxA = hann128(pxA), hxB = hann128(pxA + 64);
    float wy = (vA ? hyA : 0.0f) + (vB ? hyB : 0.0f);
    float wx = (uA ? hxA : 0.0f) + (uB ? hxB : 0.0f);

    float acc = 0.0f;
    #pragma unroll
    for (int sy = 0; sy < 2; ++sy) {
        bool okY = sy == 0 ? vA : vB;
        int nh = sy == 0 ? nhA : nhA - 1;
        int py = sy == 0 ? pyA : pyA + 64;
        #pragma unroll
        for (int sx = 0; sx < 2; ++sx) {
            bool okX = sx == 0 ? uA : uB;
            int nw = sx == 0 ? nwA : nwA - 1;
            int px = sx == 0 ? pxA : pxA + 64;
            if (okY && okX) {
                size_t off = ((((size_t)b * NPOS_ + nh * 7 + nw) * C_ + c) << 14) + (py << 7) + px;
                acc += ypatch[off];
            }
        }
    }
    out[idx] = acc / (wy * wx + 1e-8f);
}

// ---------------------------------------------------------------------------
// Kernel 3b: in-place divide (atomic fallback path)
// ---------------------------------------------------------------------------
__global__ __launch_bounds__(256) void divide_kernel(float* __restrict__ out)
{
    int idx = blockIdx.x * 256 + threadIdx.x;
    if (idx >= B_ * C_ * HW_ * HW_) return;
    int X = idx & 511;
    int Y = (idx >> 9) & 511;
    int nhA = Y >> 6, pyA = Y & 63;
    int nwA = X >> 6, pxA = X & 63;
    float wy = (nhA <= 6 ? hann128(pyA) : 0.0f) + (nhA >= 1 ? hann128(pyA + 64) : 0.0f);
    float wx = (nwA <= 6 ? hann128(pxA) : 0.0f) + (nwA >= 1 ? hann128(pxA + 64) : 0.0f);
    out[idx] = out[idx] / (wy * wx + 1e-8f);
}

extern "C" void kernel_launch(void* const* d_in, const int* in_sizes, int n_in,
                              void* d_out, int out_size, void* d_ws, size_t ws_size,
                              hipStream_t stream)
{
    const float* x    = (const float*)d_in[0];
    const float* w1   = (const float*)d_in[1];
    const float* b1   = (const float*)d_in[2];
    const float* w2   = (const float*)d_in[3];
    const float* b2   = (const float*)d_in[4];
    const float* w3   = (const float*)d_in[5];
    const float* b3   = (const float*)d_in[6];
    const float* basis = (const float*)d_in[7];
    float* out = (float*)d_out;

    unsigned int* bfrags = (unsigned int*)d_ws;
    size_t bfBytes = (size_t)NPOS_ * BPOS_U32_ * sizeof(unsigned int);   // ~3.11 MB
    size_t need = bfBytes + (size_t)BN_ * C_ * P_ * P_ * sizeof(float);  // + 77 MB

    psf_kernel<<<NPOS_, 256, 0, stream>>>(w1, b1, w2, b2, w3, b3, basis, bfrags);

    int nPix = B_ * C_ * HW_ * HW_;
    if (ws_size >= need) {
        float* ypatch = (float*)((char*)d_ws + bfBytes);
        conv_mfma_kernel<0><<<BN_ * C_, 512, 0, stream>>>(x, bfrags, ypatch);
        gather_kernel<<<(nPix + 255) / 256, 256, 0, stream>>>(ypatch, out);
    } else {
        hipMemsetAsync(d_out, 0, (size_t)out_size * sizeof(float), stream);
        conv_mfma_kernel<1><<<BN_ * C_, 512, 0, stream>>>(x, bfrags, out);
        divide_kernel<<<(nPix + 255) / 256, 256, 0, stream>>>(out);
    }
}

// Round 6
// 100.452 us; speedup vs baseline: 13.6096x; 1.2459x over previous
//
#include <hip/hip_runtime.h>
#include <math.h>

#define B_ 8
#define C_ 3
#define HW_ 512
#define P_ 128
#define S_ 64
#define K_ 31
#define NZ_ 15
#define HID_ 64
#define NPOS_ 49   // 7x7 patch positions
#define BN_ (B_*NPOS_)

#define LSTRIDE_ 168   // bf16 elems/row; 336 B = 21 x 16B blocks; 21 mod 8 = 5 (odd) -> conflict-free
#define TROWS_ 160     // 128 + 30 halo + 2 spare (rows 158,159 zero)
#define FRAG_U32_ 256  // one B fragment = 64 lanes x 16 B = 256 uints
#define NSTEP_ 16      // 16 row-pair steps cover j = 0..31 (row 31 masked to zero)
#define BPOS_U32_ (NSTEP_ * 3 * FRAG_U32_)  // 12288 uints per patch position

typedef __attribute__((ext_vector_type(8))) short bf16x8;
typedef __attribute__((ext_vector_type(4))) float f32x4;

__device__ __forceinline__ float hann128(int p) {
    return 0.5f - 0.5f * cosf(6.283185307179586f * (float)p / 128.0f);
}

__device__ __forceinline__ unsigned short bf16_rne(float f) {
    union { float f; unsigned int u; } v; v.f = f;
    unsigned int r = v.u + 0x7fffu + ((v.u >> 16) & 1u);
    return (unsigned short)(r >> 16);
}

// ---------------------------------------------------------------------------
// Kernel 1: MLP + pupil + 31x31 DFT -> normalized flipped kernel -> row-pair
// B-fragment precompute. One block per patch position (49 blocks).
// Fragment (s, c): logical k in [0,32): jrow = 2s + (k>=16),
//   B_c[k][n] = kf[jrow, 16c + (k&15) - n] if valid else 0.
// Lane labeling (matches conv A reads, empirically validated in r4/r5):
//   lane l: n = l&15, k = (l>>4)*8 + e, e = 0..7.
// ---------------------------------------------------------------------------
__global__ __launch_bounds__(256) void psf_kernel(
    const float* __restrict__ w1, const float* __restrict__ b1,
    const float* __restrict__ w2, const float* __restrict__ b2,
    const float* __restrict__ w3, const float* __restrict__ b3,
    const float* __restrict__ basis, unsigned int* __restrict__ bfrags)
{
    __shared__ float h1[HID_], h2[HID_], coef[NZ_];
    __shared__ float pupR[961], pupI[961], tR[961], tI[961];
    __shared__ float rootR[31], rootI[31];
    __shared__ float red[256];
    int n = blockIdx.x;
    int nh = n / 7, nw = n % 7;
    int tid = threadIdx.x;
    float cy = (float)(nh * S_ + P_ / 2) * (2.0f / (float)HW_) - 1.0f;
    float cx = (float)(nw * S_ + P_ / 2) * (2.0f / (float)HW_) - 1.0f;

    if (tid < HID_) h1[tid] = fmaxf(0.0f, cy * w1[tid] + cx * w1[HID_ + tid] + b1[tid]);
    if (tid < 31) {
        float ang = -6.283185307179586f * (float)tid / 31.0f;
        rootR[tid] = cosf(ang);
        rootI[tid] = sinf(ang);
    }
    __syncthreads();
    if (tid < HID_) {
        float s = b2[tid];
        for (int k = 0; k < HID_; ++k) s = fmaf(h1[k], w2[k * HID_ + tid], s);
        h2[tid] = fmaxf(0.0f, s);
    }
    __syncthreads();
    if (tid < NZ_) {
        float s = b3[tid];
        for (int k = 0; k < HID_; ++k) s = fmaf(h2[k], w3[k * NZ_ + tid], s);
        coef[tid] = s;
    }
    __syncthreads();

    for (int idx = tid; idx < 961; idx += 256) {
        int h = idx / 31, w = idx % 31;
        float ph = 0.0f;
        for (int z = 0; z < NZ_; ++z) ph = fmaf(coef[z], basis[z * 961 + idx], ph);
        int dh = h - 15, dw = w - 15;
        bool m = (dh * dh + dw * dw) <= 225;
        float sv, cv;
        sincosf(ph, &sv, &cv);
        pupR[idx] = m ? cv : 0.0f;
        pupI[idx] = m ? sv : 0.0f;
    }
    __syncthreads();

    for (int idx = tid; idx < 961; idx += 256) {
        int h = idx / 31, k = idx % 31;
        float ar = 0.0f, ai = 0.0f;
        for (int w = 0; w < 31; ++w) {
            int tt = (k * w) % 31;
            float cr = rootR[tt], ci = rootI[tt];
            float pr = pupR[h * 31 + w], pi = pupI[h * 31 + w];
            ar += pr * cr - pi * ci;
            ai += pr * ci + pi * cr;
        }
        tR[idx] = ar; tI[idx] = ai;
    }
    __syncthreads();

    float lsum = 0.0f;
    for (int idx = tid; idx < 961; idx += 256) {
        int u = idx / 31, k = idx % 31;
        float gr = 0.0f, gi = 0.0f;
        for (int h = 0; h < 31; ++h) {
            int tt = (u * h) % 31;
            float cr = rootR[tt], ci = rootI[tt];
            float ar = tR[h * 31 + k], ai = tI[h * 31 + k];
            gr += ar * cr - ai * ci;
            gi += ar * ci + ai * cr;
        }
        float p = gr * gr + gi * gi;
        pupR[idx] = p;
        lsum += p;
    }
    red[tid] = lsum;
    __syncthreads();
    for (int off = 128; off > 0; off >>= 1) {
        if (tid < off) red[tid] += red[tid + off];
        __syncthreads();
    }
    float inv = 1.0f / (red[0] + 1e-12f);
    // kf[j,i] = psf_un[(15-j)%31, (15-i)%31] * inv  -> stash in tI (free now)
    for (int idx = tid; idx < 961; idx += 256) {
        int j = idx / 31, i = idx % 31;
        int u = (15 - j + 31) % 31, v = (15 - i + 31) % 31;
        tI[idx] = pupR[u * 31 + v] * inv;
    }
    __syncthreads();

    unsigned int* bf = bfrags + (size_t)n * BPOS_U32_;
    for (int w2 = tid; w2 < BPOS_U32_; w2 += 256) {
        int jc = w2 >> 8;            // 256 uints per fragment; jc = s*3 + c
        int s = jc / 3, c = jc % 3;
        int rem = w2 & 255;
        int l = rem >> 2, ew = rem & 3;
        int nn = l & 15, kg = l >> 4;
        unsigned int pack = 0;
        #pragma unroll
        for (int q = 0; q < 2; ++q) {
            int e = ew * 2 + q;
            int kk = kg * 8 + e;
            int jrow = 2 * s + (kk >> 4);
            int tap = 16 * c + (kk & 15) - nn;
            float v = (jrow <= 30 && tap >= 0 && tap <= 30) ? tI[jrow * 31 + tap] : 0.0f;
            pack |= (unsigned int)bf16_rne(v) << (16 * q);
        }
        bf[w2] = pack;
    }
}

// ---------------------------------------------------------------------------
// Kernel 2 (v6): depthwise 31x31 conv as row-pair banded bf16 MFMA GEMM.
// One block per (patch, channel): 128x128 out, 8 waves x 16-row strips.
// Per step s (2 kernel rows): 10 ds_read_b128 A-segments (lkg<2 -> row
// m+2s, lkg>=2 -> row m+2s+1) + 3 prefetched global B-fragments + 24 MFMA.
// ---------------------------------------------------------------------------
template<int MODE>
__global__ __launch_bounds__(512) void conv_mfma_kernel(
    const float* __restrict__ x, const unsigned int* __restrict__ bfrags,
    float* __restrict__ dst)
{
    __shared__ unsigned short sIn[TROWS_ * LSTRIDE_];   // 160*168*2 = 53760 B
    __shared__ float sH[128];

    int t = blockIdx.x;
    int cc = t % 3;
    int bn = t / 3;
    int b = bn / NPOS_, n = bn % NPOS_;
    int nh = n / 7, nw = n % 7;
    int r0 = nh * S_, c0 = nw * S_;
    int tid = threadIdx.x;

    if (tid < 128) sH[tid] = hann128(tid);

    // stage patch tile (zero-padded) as bf16: rows 0..159, cols 0..159 used
    // tile[r,c] = x[r0 + r-15, c0 + c-15] if 15 <= r,c < 143 else 0
    const float* xb = x + ((size_t)(b * C_ + cc) * HW_ + r0) * HW_ + c0;
    for (int i = tid; i < TROWS_ * 40; i += 512) {
        int r = i / 40, c4 = (i % 40) * 4;
        bool rv = (r >= 15 && r < 143);
        unsigned int pk[2] = {0, 0};
        #pragma unroll
        for (int q = 0; q < 4; ++q) {
            int c = c4 + q;
            float v = 0.0f;
            if (rv && c >= 15 && c < 143) v = xb[(r - 15) * HW_ + (c - 15)];
            pk[q >> 1] |= (unsigned int)bf16_rne(v) << (16 * (q & 1));
        }
        *(uint2*)&sIn[r * LSTRIDE_ + c4] = make_uint2(pk[0], pk[1]);
    }
    __syncthreads();

    int lane = tid & 63, wv = tid >> 6;
    int m0 = wv * 16;
    int lrow = lane & 15, lkg = lane >> 4;

    f32x4 acc[8];
    #pragma unroll
    for (int q = 0; q < 8; ++q) acc[q] = (f32x4){0.f, 0.f, 0.f, 0.f};

    // A byte offset: row (m0+lrow + 2s + (lkg>>1)) * 336 + seg*32 + (lkg&1)*16
    int abase = (m0 + lrow + (lkg >> 1)) * (LSTRIDE_ * 2) + (lkg & 1) * 16;
    const bf16x8* bpos = (const bf16x8*)(bfrags + (size_t)n * BPOS_U32_) + lane;

    bf16x8 Bn0 = bpos[0], Bn1 = bpos[64], Bn2 = bpos[128];

    #pragma unroll 1
    for (int s = 0; s < NSTEP_; ++s) {
        bf16x8 B0 = Bn0, B1 = Bn1, B2 = Bn2;
        if (s < NSTEP_ - 1) {
            const bf16x8* bn = bpos + (s + 1) * 192;
            Bn0 = bn[0]; Bn1 = bn[64]; Bn2 = bn[128];
        }
        const char* ap = (const char*)sIn + abase;
        bf16x8 A[10];
        #pragma unroll
        for (int p = 0; p < 10; ++p) A[p] = *(const bf16x8*)(ap + p * 32);
        #pragma unroll
        for (int q = 0; q < 8; ++q) {
            acc[q] = __builtin_amdgcn_mfma_f32_16x16x32_bf16(A[q],     B0, acc[q], 0, 0, 0);
            acc[q] = __builtin_amdgcn_mfma_f32_16x16x32_bf16(A[q + 1], B1, acc[q], 0, 0, 0);
            acc[q] = __builtin_amdgcn_mfma_f32_16x16x32_bf16(A[q + 2], B2, acc[q], 0, 0, 0);
        }
        abase += 2 * (LSTRIDE_ * 2);
    }

    // epilogue: C/D layout col = lane&15, row = lkg*4 + r (m89-verified)
    float hy[4];
    #pragma unroll
    for (int r = 0; r < 4; ++r) hy[r] = sH[m0 + lkg * 4 + r];

    #pragma unroll
    for (int q = 0; q < 8; ++q) {
        int xloc = 16 * q + lrow;
        float hxv = sH[xloc];
        #pragma unroll
        for (int r = 0; r < 4; ++r) {
            int yloc = m0 + lkg * 4 + r;
            float val = acc[q][r] * hy[r] * hxv;
            if (MODE == 0) {
                dst[(((size_t)bn * C_ + cc) << 14) + yloc * P_ + xloc] = val;
            } else {
                atomicAdd(dst + ((size_t)(b * C_ + cc) * HW_ + r0 + yloc) * HW_ + c0 + xloc, val);
            }
        }
    }
}

// ---------------------------------------------------------------------------
// Kernel 3a: gather overlap-add (vectorized x4), divide by analytic window
// ---------------------------------------------------------------------------
__global__ __launch_bounds__(256) void gather_kernel(
    const float* __restrict__ ypatch, float* __restrict__ out)
{
    __shared__ float sH[128];
    int tid = threadIdx.x;
    if (tid < 128) sH[tid] = hann128(tid);
    __syncthreads();

    int gid = blockIdx.x * 256 + tid;
    int base = gid * 4;
    if (base >= B_ * C_ * HW_ * HW_) return;
    int X = base & 511;
    int Y = (base >> 9) & 511;
    int bc = base >> 18;
    int c = bc % 3, b = bc / 3;
    int nhA = Y >> 6, pyA = Y & 63;
    int nwA = X >> 6, pxA = X & 63;       // multiple of 4
    bool vA = nhA <= 6, vB = nhA >= 1;
    bool uA = nwA <= 6, uB = nwA >= 1;
    float wy = (vA ? sH[pyA] : 0.0f) + (vB ? sH[pyA + 64] : 0.0f);

    float4 acc = {0.f, 0.f, 0.f, 0.f};
    #pragma unroll
    for (int sy = 0; sy < 2; ++sy) {
        bool okY = sy == 0 ? vA : vB;
        int nh = sy == 0 ? nhA : nhA - 1;
        int py = sy == 0 ? pyA : pyA + 64;
        #pragma unroll
        for (int sx = 0; sx < 2; ++sx) {
            bool okX = sx == 0 ? uA : uB;
            int nw = sx == 0 ? nwA : nwA - 1;
            int px = sx == 0 ? pxA : pxA + 64;
            if (okY && okX) {
                size_t off = ((((size_t)b * NPOS_ + nh * 7 + nw) * C_ + c) << 14) + (py << 7) + px;
                float4 v = *(const float4*)&ypatch[off];
                acc.x += v.x; acc.y += v.y; acc.z += v.z; acc.w += v.w;
            }
        }
    }
    float4 o;
    float wx0 = (uA ? sH[pxA + 0] : 0.0f) + (uB ? sH[pxA + 64] : 0.0f);
    float wx1 = (uA ? sH[pxA + 1] : 0.0f) + (uB ? sH[pxA + 65] : 0.0f);
    float wx2 = (uA ? sH[pxA + 2] : 0.0f) + (uB ? sH[pxA + 66] : 0.0f);
    float wx3 = (uA ? sH[pxA + 3] : 0.0f) + (uB ? sH[pxA + 67] : 0.0f);
    o.x = acc.x / (wy * wx0 + 1e-8f);
    o.y = acc.y / (wy * wx1 + 1e-8f);
    o.z = acc.z / (wy * wx2 + 1e-8f);
    o.w = acc.w / (wy * wx3 + 1e-8f);
    *(float4*)&out[base] = o;
}

// ---------------------------------------------------------------------------
// Kernel 3b: in-place divide (atomic fallback path)
// ---------------------------------------------------------------------------
__global__ __launch_bounds__(256) void divide_kernel(float* __restrict__ out)
{
    int idx = blockIdx.x * 256 + threadIdx.x;
    if (idx >= B_ * C_ * HW_ * HW_) return;
    int X = idx & 511;
    int Y = (idx >> 9) & 511;
    int nhA = Y >> 6, pyA = Y & 63;
    int nwA = X >> 6, pxA = X & 63;
    float wy = (nhA <= 6 ? hann128(pyA) : 0.0f) + (nhA >= 1 ? hann128(pyA + 64) : 0.0f);
    float wx = (nwA <= 6 ? hann128(pxA) : 0.0f) + (nwA >= 1 ? hann128(pxA + 64) : 0.0f);
    out[idx] = out[idx] / (wy * wx + 1e-8f);
}

extern "C" void kernel_launch(void* const* d_in, const int* in_sizes, int n_in,
                              void* d_out, int out_size, void* d_ws, size_t ws_size,
                              hipStream_t stream)
{
    const float* x    = (const float*)d_in[0];
    const float* w1   = (const float*)d_in[1];
    const float* b1   = (const float*)d_in[2];
    const float* w2   = (const float*)d_in[3];
    const float* b2   = (const float*)d_in[4];
    const float* w3   = (const float*)d_in[5];
    const float* b3   = (const float*)d_in[6];
    const float* basis = (const float*)d_in[7];
    float* out = (float*)d_out;

    unsigned int* bfrags = (unsigned int*)d_ws;
    size_t bfBytes = (size_t)NPOS_ * BPOS_U32_ * sizeof(unsigned int);   // ~2.41 MB
    size_t need = bfBytes + (size_t)BN_ * C_ * P_ * P_ * sizeof(float);  // + 77 MB

    psf_kernel<<<NPOS_, 256, 0, stream>>>(w1, b1, w2, b2, w3, b3, basis, bfrags);

    int nPix = B_ * C_ * HW_ * HW_;
    if (ws_size >= need) {
        float* ypatch = (float*)((char*)d_ws + bfBytes);
        conv_mfma_kernel<0><<<BN_ * C_, 512, 0, stream>>>(x, bfrags, ypatch);
        gather_kernel<<<(nPix / 4 + 255) / 256, 256, 0, stream>>>(ypatch, out);
    } else {
        hipMemsetAsync(d_out, 0, (size_t)out_size * sizeof(float), stream);
        conv_mfma_kernel<1><<<BN_ * C_, 512, 0, stream>>>(x, bfrags, out);
        divide_kernel<<<(nPix + 255) / 256, 256, 0, stream>>>(out);
    }
}